// Round 11
// baseline (1332.000 us; speedup 1.0000x reference)
//
// R14: R12 consumer structure (proven best: 1129-1151us dispatches) +
// producer-side per-wave early signal + double-buffered inA.
// R13 post-mortem: de-lockstep regressed (+85us) but bundled TWO changes;
// the consumer-side all-wave 2-serial-spin polls are the indicted half
// (serialize waits R12 polled in parallel, 4x poll traffic; counters show
// pure sync-path regression). R14 keeps R13's sound half only:
//  - producer: each wave drains own stores (vmcnt(0), proven asm) and lane0
//    stores its subflag -> end-of-step barrier deleted (2 barriers/step).
//  - inA double-buffered [2][MB][LDSK] (134KB LDS, proven R13) -> early waves
//    stage step t+1 while stragglers finish t; race-free by barrier order.
//  - consumer: R12 VERBATIM (wave0 lanes<32 parallel poll + 1 barrier +
//    inv_l1); readiness = min over the wg's 4 subflags (4 adjacent sc1
//    loads/spin, same thresholds -> same dependency DAG).
//  - discovery ids -> group padding (offset 64..79 of each 256-int group,
//    barrier cnt[80]); subflags at offsets 0..63. No collisions; all zeroed.
//  - slow path: R12's 3 barriers + per-wave sc1 subflags (stronger, safe).
#include <hip/hip_runtime.h>
#include <cstdint>

#define B_TOT 256
#define T_LEN 512
#define NX    40
#define NH    250
#define HP    256          // hidden padded (dummy units produce h=0, W cols 0)
#define XP    64           // x padded
#define K0    (XP + HP)    // 320  (layer0: [x | h1_prev])
#define K1    (HP + HP)    // 512  (layer1: [h1_t | h2_prev])
#define MB    32           // batches per wg
#define NU    16           // hidden units per wg
#define NR    64           // gate rows per wg (NU*4, r = lu*4 + gate; i,f,g,o)
#define RING  8            // broadcast ring depth
#define LDSK  520          // LDS K-stride in ushorts (16B aligned; 260 dwords)
#define NFLAG 4096         // 16 groups x 256 ints = 16KB (same footprint)
#define GSTRIDE 256        // ints per (layer,gb) group
// group layout (ints): [0..63] subflags (wg-major: wg*4 + wave),
//                      [64..79] discovery xcd ids, [80] grid barrier (grp 0),
//                      rest padding. All zeroed by prep_zero each launch.
#define RSTEP (B_TOT * HP / 2)       // 32768 dwords per ring slot
// h ring (dwords): slot*RSTEP + gb*4096 + gg*256 + eb*8 + up
//   where dword (gg,up) of batch eb = bf16 units (gg*16+2up, gg*16+2up+1)
#define XCD_AT(w) (((w) >> 4) * GSTRIDE + 64 + ((w) & 15))
#define BAR_IDX 80
// s_getreg imm: id | (offset<<6) | ((size-1)<<11); XCC_ID id=20, 32 bits.
#define GETREG_XCC 63508

typedef __attribute__((ext_vector_type(8))) short short8;
typedef __attribute__((ext_vector_type(4))) float float4v;

__device__ __forceinline__ unsigned short f2bf(float f) {
  unsigned u = __float_as_uint(f);
  u += 0x7FFFu + ((u >> 16) & 1u);          // RNE
  return (unsigned short)(u >> 16);
}
__device__ __forceinline__ float bf2f(unsigned short h) {
  return __uint_as_float(((unsigned)h) << 16);
}
__device__ __forceinline__ float sigm(float x) { return 1.0f / (1.0f + __expf(-x)); }
__device__ __forceinline__ float tanh_f(float x) {
  float e = __expf(-2.0f * fabsf(x));
  float t = (1.0f - e) / (1.0f + e);
  return copysignf(t, x);
}
__device__ __forceinline__ int ld_flag(const int* p) {            // sc1 dword load
  return __hip_atomic_load(p, __ATOMIC_RELAXED, __HIP_MEMORY_SCOPE_AGENT);
}
// wg readiness = min over its 4 per-wave subflags (each monotone -> safe)
__device__ __forceinline__ int min4_flag(const int* p) {
  int a = ld_flag(p + 0), b = ld_flag(p + 1);
  int c = ld_flag(p + 2), d = ld_flag(p + 3);
  return min(min(a, b), min(c, d));
}
__device__ __forceinline__ unsigned ld_lic(const unsigned* p) {
  return __hip_atomic_load(p, __ATOMIC_RELAXED, __HIP_MEMORY_SCOPE_AGENT);
}
// CU-local L1 invalidate: subsequent plain loads are (at least) L2-fresh.
__device__ __forceinline__ void inv_l1() {
  asm volatile("buffer_inv\n\ts_waitcnt vmcnt(0)" ::: "memory");
  __builtin_amdgcn_sched_barrier(0);
}
// in-wave store drain: own stores acked at L2 before the subflag store
__device__ __forceinline__ void drain_vm() {
  asm volatile("s_waitcnt vmcnt(0)" ::: "memory");
  __builtin_amdgcn_sched_barrier(0);
}
template <bool FAST>
__device__ __forceinline__ unsigned ldh(const unsigned* p) {
  if (FAST) return *p;     // plain load, L2-served (post-inv)
  return ld_lic(p);
}
template <bool FAST>
__device__ __forceinline__ void sth(unsigned* p, unsigned v) {
  if (FAST) *p = v;        // plain store: write-through L1 -> local L2
  else __hip_atomic_store(p, v, __ATOMIC_RELAXED, __HIP_MEMORY_SCOPE_AGENT);
}

// ---------------------------------------------------------------------------
// Per-layer persistent loop. LAYER=0: x(40->64 pad)+h1_prev, K=320.
// LAYER=1: h1_t + h2_prev, K=512; every layer1 wg emits y for 2 batches.
// Subflag (wg gg, wave w) value = steps completed by that wave.
// ---------------------------------------------------------------------------
template <int KSTEPS, int LAYER, bool FAST>
__device__ __forceinline__ void run_layer(
    int tid, int gg, int b0, int u0,
    const float* __restrict__ x, float* __restrict__ out, float blinv,
    unsigned short* __restrict__ h1bc, unsigned short* __restrict__ h2bc,
    int* __restrict__ c0s, int* __restrict__ c1s,
    unsigned short (*WL)[LDSK], unsigned short (*inA2)[LDSK],
    float* biasS, float* wlinS) {
  const int lane = tid & 63, wv = tid >> 6;
  const int quad = lane >> 4, l15 = lane & 15;
  const int Mt = wv & 1, Np = wv >> 1;   // wave -> (batch-tile, r-tile-pair)
  const int gb = b0 >> 5;
  const int irow = tid >> 3, icol = tid & 7;   // gather->LDS scatter coords

  int* mysub = (LAYER ? c1s : c0s) + gg * 4 + wv;

  // Preload W fragments (constant across time), MFMA A-operand (R12-proven).
  short8 wfrag[2][KSTEPS];
#pragma unroll
  for (int ks = 0; ks < KSTEPS; ++ks) {
#pragma unroll
    for (int i = 0; i < 2; ++i)
      wfrag[i][ks] = *(const short8*)&WL[Np * 32 + i * 16 + l15][ks * 32 + quad * 8];
  }

  // gate biases for this lane's rows (R12-proven layout)
  float4v b4A = *(const float4v*)&biasS[Np * 32 + quad * 4];
  float4v b4B = *(const float4v*)&biasS[Np * 32 + 16 + quad * 4];

  // x prefetch registers (layer0, threads 0..127): holds x[t] during step t-1
  float xr[10];
  if (LAYER == 0 && tid < 128) {
    int b = tid >> 2, c = tid & 3;
    const float* xp0 = x + ((size_t)(b0 + b) * T_LEN + 0) * NX + c * 10;
#pragma unroll
    for (int j = 0; j < 10; ++j) xr[j] = xp0[j];
  }

  // cell state: lane owns (unit Np*8+quad, batch Mt*16+l15) -> cA; +4 -> cB
  float cA = 0.f, cB = 0.f;

#pragma unroll 1
  for (int t = 0; t < T_LEN; ++t) {
    // ---- wait for producers: R12-verbatim wave0 parallel poll; wg
    //      readiness = min over its 4 subflags. Thresholds identical to R12.
    if (wv == 0 && lane < 32) {
      const int* sl = ((lane < 16) ? c0s : c1s) + (lane & 15) * 4;
      int thr;
      if (LAYER == 0) thr = (lane < 16) ? t : (t - RING + 1);
      else            thr = (lane < 16) ? (t + 1) : t;
      while (min4_flag(sl) < thr) {
        __builtin_amdgcn_s_sleep(1);
      }
    }
    __syncthreads();                                // barrier #1 (post-poll)
    if (FAST && (LAYER == 1 || t > 0)) inv_l1();    // R12-proven placement

    unsigned short (*inbuf)[LDSK] = inA2 + (t & 1) * MB;   // double buffer

    // ---- stage inputs into LDS (bf16); scalar dword gather (proven) ----
    if (LAYER == 0) {
      if (t > 0) {
        const unsigned* s1 = (const unsigned*)h1bc +
            ((size_t)((t - 1) & (RING - 1)) * RSTEP + (size_t)gb * 4096);
        unsigned v[16];
#pragma unroll
        for (int k = 0; k < 16; ++k) v[k] = ldh<FAST>(s1 + tid + k * 256);
#pragma unroll
        for (int k = 0; k < 16; ++k)   // dword (gg=k, up=icol) of batch irow
          ((unsigned*)&inbuf[irow][0])[32 + k * 8 + icol] = v[k];   // +XP
      }
      if (tid < 128) {   // x[b,t,0:40] from prefetch regs (40..63 stay zero)
        int b = tid >> 2, c = tid & 3;
#pragma unroll
        for (int j = 0; j < 10; ++j) inbuf[b][c * 10 + j] = f2bf(xr[j]);
      }
    } else {
      const unsigned* s1 = (const unsigned*)h1bc +
          ((size_t)(t & (RING - 1)) * RSTEP + (size_t)gb * 4096);
      unsigned va[16], vb[16];
#pragma unroll
      for (int k = 0; k < 16; ++k) va[k] = ldh<FAST>(s1 + tid + k * 256);
      if (t > 0) {
        const unsigned* s2 = (const unsigned*)h2bc +
            ((size_t)((t - 1) & (RING - 1)) * RSTEP + (size_t)gb * 4096);
#pragma unroll
        for (int k = 0; k < 16; ++k) vb[k] = ldh<FAST>(s2 + tid + k * 256);
      }
#pragma unroll
      for (int k = 0; k < 16; ++k) {
        unsigned* row = (unsigned*)&inbuf[irow][0];
        row[k * 8 + icol] = va[k];                    // h1 at ushort 0
        if (t > 0) row[128 + k * 8 + icol] = vb[k];   // h2 at ushort HP
      }
    }
    __syncthreads();   // barrier #2: staging -> MFMA

    // ---- prefetch x[t+1] into regs (R12-proven placement) ----
    if (LAYER == 0 && tid < 128 && t + 1 < T_LEN) {
      int b = tid >> 2, c = tid & 3;
      const float* xp = x + ((size_t)(b0 + b) * T_LEN + (size_t)(t + 1)) * NX + c * 10;
#pragma unroll
      for (int j = 0; j < 10; ++j) xr[j] = xp[j];
    }

    // ---- gate GEMM, operand-swapped: D[r][b] (R12-proven) ----
    float4v acc0 = {0.f, 0.f, 0.f, 0.f};
    float4v acc1 = {0.f, 0.f, 0.f, 0.f};
#pragma unroll
    for (int ks = 0; ks < KSTEPS; ++ks) {
      short8 a = *(const short8*)&inbuf[Mt * 16 + l15][ks * 32 + quad * 8];
      acc0 = __builtin_amdgcn_mfma_f32_16x16x32_bf16(wfrag[0][ks], a, acc0, 0, 0, 0);
      acc1 = __builtin_amdgcn_mfma_f32_16x16x32_bf16(wfrag[1][ks], a, acc1, 0, 0, 0);
    }

    // ---- gates in-register (R12-proven lane layout) ----
    float hA, hB;
    {
      float i0 = sigm(acc0[0] + b4A[0]);
      float f0 = sigm(acc0[1] + b4A[1]);
      float g0 = tanh_f(acc0[2] + b4A[2]);
      float o0 = sigm(acc0[3] + b4A[3]);
      cA = f0 * cA + i0 * g0;
      hA = o0 * tanh_f(cA);
      float i1 = sigm(acc1[0] + b4B[0]);
      float f1 = sigm(acc1[1] + b4B[1]);
      float g1 = tanh_f(acc1[2] + b4B[2]);
      float o1 = sigm(acc1[3] + b4B[3]);
      cB = f1 * cB + i1 * g1;
      hB = o1 * tanh_f(cB);
    }
    // pack unit pairs (lane^16) and store to the ring (R12-proven mapping)
    {
      float hA2 = __shfl_xor(hA, 16);
      float hB2 = __shfl_xor(hB, 16);
      if ((quad & 1) == 0) {
        unsigned dwA = (unsigned)f2bf(hA) | ((unsigned)f2bf(hA2) << 16);
        unsigned dwB = (unsigned)f2bf(hB) | ((unsigned)f2bf(hB2) << 16);
        unsigned* dst = (unsigned*)(LAYER ? h2bc : h1bc);
        size_t base = (size_t)(t & (RING - 1)) * RSTEP + (size_t)gb * 4096 +
                      (size_t)gg * 256 + (size_t)(Mt * 16 + l15) * 8;
        sth<FAST>(dst + base + Np * 4 + (quad >> 1), dwA);
        sth<FAST>(dst + base + Np * 4 + 2 + (quad >> 1), dwB);
      }
    }

    // ---- signal: FAST = per-wave (drain own stores incl. x prefetch is
    //      harmless, lane0 subflag, NO end barrier); slow = barrier then
    //      per-wave sc1 subflag (R12-equivalent, stronger).
    if (FAST) {
      drain_vm();
      if (lane == 0) sth<true>((unsigned*)mysub, (unsigned)(t + 1));
    } else {
      __syncthreads();
      if (lane == 0) sth<false>((unsigned*)mysub, (unsigned)(t + 1));
    }

    // ---- head: y[b, t-1] — distributed (2 batches/wg), after signal ----
    if (LAYER == 1 && t > 0 && tid < 16) {
      int eb2 = 2 * gg + (tid >> 3), uc = tid & 7;
      float sum = 0.f;
#pragma unroll
      for (int j = 0; j < 4; ++j) {
        short8 hvv = *(const short8*)&inbuf[eb2][HP + uc * 32 + j * 8];
#pragma unroll
        for (int e = 0; e < 8; ++e)
          sum += bf2f((unsigned short)hvv[e]) * wlinS[uc * 32 + j * 8 + e];
      }
      sum += __shfl_xor(sum, 1);
      sum += __shfl_xor(sum, 2);
      sum += __shfl_xor(sum, 4);
      if ((tid & 7) == 0)
        out[(size_t)(b0 + eb2) * T_LEN + (t - 1)] = sigm(sum + blinv);
    }
  }

  // ---- epilogue: y[:, 511] — distributed: every layer1 wg, 2 batches ----
  if (LAYER == 1) {
    if (wv == 0 && lane < 16) {
      const int* sl = c1s + lane * 4;
      while (min4_flag(sl) < T_LEN) __builtin_amdgcn_s_sleep(1);
    }
    __syncthreads();
    if (FAST) inv_l1();
    if (tid < 16) {
      int eb2 = 2 * gg + (tid >> 3), uc = tid & 7;
      const unsigned* base = (const unsigned*)h2bc +
          ((size_t)(511 & (RING - 1)) * RSTEP + (size_t)gb * 4096);
      float sum = 0.f;
#pragma unroll
      for (int g = 0; g < 2; ++g) {
        const unsigned* src = base + (size_t)(2 * uc + g) * 256 + eb2 * 8;
#pragma unroll
        for (int j = 0; j < 8; ++j) {
          unsigned dw = ldh<FAST>(src + j);
          sum += bf2f((unsigned short)(dw & 0xFFFFu)) * wlinS[uc * 32 + g * 16 + 2 * j];
          sum += bf2f((unsigned short)(dw >> 16)) * wlinS[uc * 32 + g * 16 + 2 * j + 1];
        }
      }
      sum += __shfl_xor(sum, 1);
      sum += __shfl_xor(sum, 2);
      sum += __shfl_xor(sum, 4);
      if ((tid & 7) == 0)
        out[(size_t)(b0 + eb2) * T_LEN + 511] = sigm(sum + blinv);
    }
  }
}

// ---------------------------------------------------------------------------
extern "C" __global__ void __launch_bounds__(256, 1) lstm_persist(
    const float* __restrict__ x,
    const float* __restrict__ Wih0, const float* __restrict__ Whh0,
    const float* __restrict__ bih0, const float* __restrict__ bhh0,
    const float* __restrict__ Wih1, const float* __restrict__ Whh1,
    const float* __restrict__ bih1, const float* __restrict__ bhh1,
    const float* __restrict__ Wlin, const float* __restrict__ blin,
    float* __restrict__ out,
    unsigned short* __restrict__ h1bc, unsigned short* __restrict__ h2bc,
    int* __restrict__ cnt) {
  __shared__ unsigned short WL[NR][LDSK];      // 66560 B  bf16 [r][k]
  __shared__ unsigned short inA[2 * MB][LDSK]; // 66560 B  double-buffered acts
  __shared__ float biasS[NR];
  __shared__ float wlinS[HP];

  const int tid = threadIdx.x;
  const int wg = blockIdx.x;

  // ---- XCD discovery + dynamic clustering (one-time, off steady state) ----
  const unsigned xcc = ((unsigned)__builtin_amdgcn_s_getreg(GETREG_XCC)) & 15u;
  if (tid == 0) {
    __hip_atomic_store(cnt + XCD_AT(wg), (int)xcc, __ATOMIC_RELAXED,
                       __HIP_MEMORY_SCOPE_AGENT);
    __hip_atomic_fetch_add(cnt + BAR_IDX, 1, __ATOMIC_ACQ_REL,
                           __HIP_MEMORY_SCOPE_AGENT);
    while (__hip_atomic_load(cnt + BAR_IDX, __ATOMIC_ACQUIRE,
                             __HIP_MEMORY_SCOPE_AGENT) < 256)
      __builtin_amdgcn_s_sleep(8);
  }
  __syncthreads();
  int* sx = (int*)&inA[0][0];   // inA as 256-int scratch (pre-zeroing)
  sx[tid] = __hip_atomic_load(cnt + XCD_AT(tid), __ATOMIC_RELAXED,
                              __HIP_MEMORY_SCOPE_AGENT);
  __syncthreads();
  const int myv = sx[wg];
  int rank = 0;
  unsigned long long hist = 0;
  bool ok = true;
  for (int j = 0; j < 256; ++j) {
    int v = sx[j];
    if ((unsigned)v > 7u) { ok = false; v = 0; }
    hist += 1ull << (v * 8);
    if (v == myv && j < wg) rank++;
  }
  ok = ok && (hist == 0x2020202020202020ull);   // exactly 32 wgs per XCD
  __syncthreads();   // sx (inA) free for zero-fill below

  // Roles: fast -> cluster = this XCD; slow -> static mapping + sc1 ops.
  int layer, gb, gg;
  if (ok) { gb = myv;       layer = rank >> 4;    gg = rank & 15; }
  else    { layer = wg >> 7; gb = (wg >> 4) & 7;  gg = wg & 15;   }
  const int b0 = gb * MB, u0 = gg * NU;

  // ---- one-time LDS fills ----
  {
    const float* Wih = layer ? Wih1 : Wih0;
    const float* Whh = layer ? Whh1 : Whh0;
    const float* bi = layer ? bih1 : bih0;
    const float* bh = layer ? bhh1 : bhh0;
    const int K = layer ? K1 : K0;
    const int xw = layer ? NH : NX;     // real width of input-part
    const int xofs = layer ? HP : XP;   // where h-part starts
    int r = tid >> 2, c = tid & 3;
    int lu = r >> 2, g = r & 3, ug = u0 + lu;
    int row = g * NH + ug;
    int kq = K >> 2;
    for (int k = c * kq; k < (c + 1) * kq; ++k) {
      float v = 0.f;
      if (ug < NH) {
        if (k < xw) v = Wih[(size_t)row * xw + k];
        else if (k >= xofs && k < xofs + NH) v = Whh[(size_t)row * NH + (k - xofs)];
      }
      WL[r][k] = f2bf(v);
    }
    if (tid < NR) {
      int lu2 = tid >> 2, g2 = tid & 3, ug2 = u0 + lu2;
      biasS[tid] = (ug2 < NH) ? (bi[g2 * NH + ug2] + bh[g2 * NH + ug2]) : 0.f;
    }
    if (tid < HP) wlinS[tid] = (tid < NH) ? Wlin[tid] : 0.f;
    for (int i = tid; i < 2 * MB * LDSK; i += 256) ((unsigned short*)inA)[i] = 0;
  }
  __syncthreads();

  float blinv = blin[0];
  int* c0s = cnt + gb * GSTRIDE;            // layer0 subflags, batch-group gb
  int* c1s = cnt + (8 + gb) * GSTRIDE;      // layer1 subflags

  if (ok) {
    if (layer == 0)
      run_layer<K0 / 32, 0, true>(tid, gg, b0, u0, x, out, blinv, h1bc, h2bc,
                                  c0s, c1s, WL, inA, biasS, wlinS);
    else
      run_layer<K1 / 32, 1, true>(tid, gg, b0, u0, x, out, blinv, h1bc, h2bc,
                                  c0s, c1s, WL, inA, biasS, wlinS);
  } else {
    if (layer == 0)
      run_layer<K0 / 32, 0, false>(tid, gg, b0, u0, x, out, blinv, h1bc, h2bc,
                                   c0s, c1s, WL, inA, biasS, wlinS);
    else
      run_layer<K1 / 32, 1, false>(tid, gg, b0, u0, x, out, blinv, h1bc, h2bc,
                                   c0s, c1s, WL, inA, biasS, wlinS);
  }
}

extern "C" __global__ void prep_zero(int* cnt) {
  int i = blockIdx.x * 256 + threadIdx.x;
  if (i < NFLAG)   // subflags + discovery ids + grid-barrier int
    __hip_atomic_store(cnt + i, 0, __ATOMIC_RELAXED, __HIP_MEMORY_SCOPE_AGENT);
}

// ---------------------------------------------------------------------------
extern "C" void kernel_launch(void* const* d_in, const int* in_sizes, int n_in,
                              void* d_out, int out_size, void* d_ws, size_t ws_size,
                              hipStream_t stream) {
  const float* x    = (const float*)d_in[0];
  const float* Wih0 = (const float*)d_in[1];
  const float* Whh0 = (const float*)d_in[2];
  const float* bih0 = (const float*)d_in[3];
  const float* bhh0 = (const float*)d_in[4];
  const float* Wih1 = (const float*)d_in[5];
  const float* Whh1 = (const float*)d_in[6];
  const float* bih1 = (const float*)d_in[7];
  const float* bhh1 = (const float*)d_in[8];
  const float* Wlin = (const float*)d_in[9];
  const float* blin = (const float*)d_in[10];
  float* out = (float*)d_out;

  // workspace carve (same footprint as R3..R13): h rings 2x2MB | flags 16KB
  unsigned short* h1bc = (unsigned short*)d_ws;
  unsigned short* h2bc = h1bc + (size_t)RING * B_TOT * HP;
  int* cnt = (int*)((char*)d_ws + 2u * (size_t)RING * B_TOT * HP * sizeof(unsigned short));

  hipLaunchKernelGGL(prep_zero, dim3(16), dim3(256), 0, stream, cnt);

  void* args[] = {&x, &Wih0, &Whh0, &bih0, &bhh0, &Wih1, &Whh1, &bih1, &bhh1,
                  &Wlin, &blin, &out, &h1bc, &h2bc, &cnt};
  hipLaunchCooperativeKernel((void*)lstm_persist, dim3(256), dim3(256), args, 0u, stream);
}

// Round 12
// 1079.507 us; speedup vs baseline: 1.2339x; 1.2339x over previous
//
// R15: R12 sync skeleton (proven best 1129-1188us; R13/R14 de-locksteps both
// regressed -> sync frozen) + MFMA A-operands loaded DIRECTLY from the L2
// ring, deleting the LDS staging round-trip.
// Key algebra: swapped-MFMA lane (quad,l15) of wave (Mt,Np) needs activation
// ushorts ks*32+quad*8..+8 of batch eb=Mt*16+l15 = ring dwords
// g*256 + eb*8 + (quad&1)*4 .. +4 with g = 2ks+(quad>>1)  (4 consecutive
// dwords, one dwordx4; 64 lanes = 1KB contiguous -> fully coalesced).
//  - layer1 (bottleneck, K=512): NO LDS staging; poll->bar->inv->16 dwordx4 +
//    32 MFMA->gates->store->bar->flag (2 barriers, zero LDS traffic). Head
//    reads h2[t-1] from the ring (epilogue-proven mapping; overwrite is 7
//    pipeline steps away).
//  - layer0: stages only x ([32][72] ushorts, 2-way-free banks); h1_prev via
//    8 direct dwordx4 in the compute phase; 3 barriers (R12 placements).
//  - slow path: same structure, dwordx4 emulated by 4 sc1 dword loads.
// Predicted: dur -100..-250us; SQ_LDS_BANK_CONFLICT 5.6e7 -> <1.5e7.
#include <hip/hip_runtime.h>
#include <cstdint>

#define B_TOT 256
#define T_LEN 512
#define NX    40
#define NH    250
#define HP    256          // hidden padded (dummy units produce h=0, W cols 0)
#define XP    64           // x padded
#define K0    (XP + HP)    // 320  (layer0: [x | h1_prev])
#define K1    (HP + HP)    // 512  (layer1: [h1_t | h2_prev])
#define MB    32           // batches per wg
#define NU    16           // hidden units per wg
#define NR    64           // gate rows per wg (NU*4, r = lu*4 + gate; i,f,g,o)
#define RING  8            // broadcast ring depth
#define LDSK  520          // W LDS K-stride in ushorts (16B aligned)
#define XLDS  72           // x LDS row stride (144B -> 2-way banks = free)
#define SLOTS 16           // ints per flag slot (64B stride) [R12 layout]
#define NFLAG (2 * 8 * 16 * SLOTS)   // 4096 ints (16KB)
#define RSTEP (B_TOT * HP / 2)       // 32768 dwords per ring slot
// h ring (dwords): slot*RSTEP + gb*4096 + gg*256 + eb*8 + up
//   where dword (gg,up) of batch eb = bf16 units (gg*16+2up, gg*16+2up+1)
#define XCD_AT(w) ((w) * SLOTS + 8)
#define BAR_IDX 9
// s_getreg imm: id | (offset<<6) | ((size-1)<<11); XCC_ID id=20, 32 bits.
#define GETREG_XCC 63508

typedef __attribute__((ext_vector_type(8))) short short8;
typedef __attribute__((ext_vector_type(4))) float float4v;

__device__ __forceinline__ unsigned short f2bf(float f) {
  unsigned u = __float_as_uint(f);
  u += 0x7FFFu + ((u >> 16) & 1u);          // RNE
  return (unsigned short)(u >> 16);
}
__device__ __forceinline__ float bf2f(unsigned short h) {
  return __uint_as_float(((unsigned)h) << 16);
}
__device__ __forceinline__ float sigm(float x) { return 1.0f / (1.0f + __expf(-x)); }
__device__ __forceinline__ float tanh_f(float x) {
  float e = __expf(-2.0f * fabsf(x));
  float t = (1.0f - e) / (1.0f + e);
  return copysignf(t, x);
}
__device__ __forceinline__ unsigned ld_lic(const unsigned* p) {   // sc1 dword load
  return __hip_atomic_load(p, __ATOMIC_RELAXED, __HIP_MEMORY_SCOPE_AGENT);
}
// CU-local L1 invalidate: subsequent plain loads are (at least) L2-fresh.
__device__ __forceinline__ void inv_l1() {
  asm volatile("buffer_inv\n\ts_waitcnt vmcnt(0)" ::: "memory");
  __builtin_amdgcn_sched_barrier(0);
}
template <bool FAST>
__device__ __forceinline__ unsigned ldh(const unsigned* p) {
  if (FAST) return *p;     // plain load, L2-served (post-inv)
  return ld_lic(p);
}
template <bool FAST>
__device__ __forceinline__ uint4 ldh4(const unsigned* p) {
  if (FAST) return *(const uint4*)p;   // dwordx4, L2-served (post-inv)
  uint4 v;
  v.x = ld_lic(p + 0); v.y = ld_lic(p + 1);
  v.z = ld_lic(p + 2); v.w = ld_lic(p + 3);
  return v;
}
template <bool FAST>
__device__ __forceinline__ void sth(unsigned* p, unsigned v) {
  if (FAST) *p = v;        // plain store: write-through L1 -> local L2
  else __hip_atomic_store(p, v, __ATOMIC_RELAXED, __HIP_MEMORY_SCOPE_AGENT);
}

// ---------------------------------------------------------------------------
// Per-layer persistent loop. LAYER=0: x(40->64 pad)+h1_prev, K=320.
// LAYER=1: h1_t + h2_prev, K=512; every layer1 wg emits y for 2 batches.
// Flag value (one per wg, R12 layout) = steps completed by that wg.
// ---------------------------------------------------------------------------
template <int KSTEPS, int LAYER, bool FAST>
__device__ __forceinline__ void run_layer(
    int tid, int gg, int b0, int u0,
    const float* __restrict__ x, float* __restrict__ out, float blinv,
    unsigned short* __restrict__ h1bc, unsigned short* __restrict__ h2bc,
    int* __restrict__ c0s, int* __restrict__ c1s, int* __restrict__ mys,
    unsigned short (*WL)[LDSK], unsigned short (*xA)[XLDS],
    float* biasS, float* wlinS) {
  const int lane = tid & 63, wv = tid >> 6;
  const int quad = lane >> 4, l15 = lane & 15;
  const int Mt = wv & 1, Np = wv >> 1;   // wave -> (batch-tile, r-tile-pair)
  const int gb = b0 >> 5;
  // direct-load lane offset inside a ring block-pair:
  //   dword = (2ks + (quad>>1))*256 + eb*8 + (quad&1)*4,  eb = Mt*16+l15
  const int lofs = (quad >> 1) * 256 + (Mt * 16 + l15) * 8 + (quad & 1) * 4;
  constexpr int NHF = LAYER ? KSTEPS : (KSTEPS - 2);   // h-fragments count

  // Preload W fragments (constant across time), MFMA A-operand (R12-proven).
  short8 wfrag[2][KSTEPS];
#pragma unroll
  for (int ks = 0; ks < KSTEPS; ++ks) {
#pragma unroll
    for (int i = 0; i < 2; ++i)
      wfrag[i][ks] = *(const short8*)&WL[Np * 32 + i * 16 + l15][ks * 32 + quad * 8];
  }

  // gate biases for this lane's rows (R12-proven layout)
  float4v b4A = *(const float4v*)&biasS[Np * 32 + quad * 4];
  float4v b4B = *(const float4v*)&biasS[Np * 32 + 16 + quad * 4];

  // x prefetch registers (layer0, threads 0..127): holds x[t] during step t-1
  float xr[10];
  if (LAYER == 0 && tid < 128) {
    int b = tid >> 2, c = tid & 3;
    const float* xp0 = x + ((size_t)(b0 + b) * T_LEN + 0) * NX + c * 10;
#pragma unroll
    for (int j = 0; j < 10; ++j) xr[j] = xp0[j];
  }

  // cell state: lane owns (unit Np*8+quad, batch Mt*16+l15) -> cA; +4 -> cB
  float cA = 0.f, cB = 0.f;

#pragma unroll 1
  for (int t = 0; t < T_LEN; ++t) {
    // ---- wait for producers: R12-verbatim wave0 parallel poll ----
    if (wv == 0 && lane < 32) {
      const int* sl = ((lane < 16) ? c0s : c1s) + (lane & 15) * SLOTS;
      int thr;
      if (LAYER == 0) thr = (lane < 16) ? t : (t - RING + 1);
      else            thr = (lane < 16) ? (t + 1) : t;
      while (__hip_atomic_load(sl, __ATOMIC_RELAXED, __HIP_MEMORY_SCOPE_AGENT) < thr) {
        __builtin_amdgcn_s_sleep(1);
      }
    }
    __syncthreads();                                // barrier #1 (post-poll)
    if (FAST && (LAYER == 1 || t > 0)) inv_l1();    // R12-proven placement

    // ---- layer0 only: stage x[t] into LDS (tiny), then x[t+1] prefetch ----
    if (LAYER == 0) {
      if (tid < 128) {   // x[b,t,0:40] from prefetch regs (40..63 stay zero)
        int b = tid >> 2, c = tid & 3;
#pragma unroll
        for (int j = 0; j < 10; ++j) xA[b][c * 10 + j] = f2bf(xr[j]);
      }
      __syncthreads();   // barrier #2: x-stage -> MFMA
      if (tid < 128 && t + 1 < T_LEN) {
        int b = tid >> 2, c = tid & 3;
        const float* xp = x + ((size_t)(b0 + b) * T_LEN + (size_t)(t + 1)) * NX + c * 10;
#pragma unroll
        for (int j = 0; j < 10; ++j) xr[j] = xp[j];
      }
    }

    // ---- direct ring loads of h fragments (dwordx4 per lane per ks) ----
    uint4 hfr[NHF];
    if (LAYER == 0) {
      if (t > 0) {
        const unsigned* b1 = (const unsigned*)h1bc +
            ((size_t)((t - 1) & (RING - 1)) * RSTEP + (size_t)gb * 4096) + lofs;
#pragma unroll
        for (int i = 0; i < NHF; ++i) hfr[i] = ldh4<FAST>(b1 + i * 512);
      } else {
#pragma unroll
        for (int i = 0; i < NHF; ++i) hfr[i] = uint4{0, 0, 0, 0};
      }
    } else {
      const unsigned* b1 = (const unsigned*)h1bc +
          ((size_t)(t & (RING - 1)) * RSTEP + (size_t)gb * 4096) + lofs;
#pragma unroll
      for (int i = 0; i < 8; ++i) hfr[i] = ldh4<FAST>(b1 + i * 512);
      if (t > 0) {
        const unsigned* b2 = (const unsigned*)h2bc +
            ((size_t)((t - 1) & (RING - 1)) * RSTEP + (size_t)gb * 4096) + lofs;
#pragma unroll
        for (int i = 0; i < 8; ++i) hfr[8 + i] = ldh4<FAST>(b2 + i * 512);
      } else {
#pragma unroll
        for (int i = 0; i < 8; ++i) hfr[8 + i] = uint4{0, 0, 0, 0};
      }
    }

    // ---- gate GEMM, operand-swapped: D[r][b] (R12-proven layout) ----
    float4v acc0 = {0.f, 0.f, 0.f, 0.f};
    float4v acc1 = {0.f, 0.f, 0.f, 0.f};
    if (LAYER == 0) {
#pragma unroll
      for (int ks = 0; ks < 2; ++ks) {   // x part from LDS
        short8 a = *(const short8*)&xA[Mt * 16 + l15][ks * 32 + quad * 8];
        acc0 = __builtin_amdgcn_mfma_f32_16x16x32_bf16(wfrag[0][ks], a, acc0, 0, 0, 0);
        acc1 = __builtin_amdgcn_mfma_f32_16x16x32_bf16(wfrag[1][ks], a, acc1, 0, 0, 0);
      }
#pragma unroll
      for (int i = 0; i < NHF; ++i) {    // h1_prev direct
        short8 a = *(const short8*)&hfr[i];
        acc0 = __builtin_amdgcn_mfma_f32_16x16x32_bf16(wfrag[0][2 + i], a, acc0, 0, 0, 0);
        acc1 = __builtin_amdgcn_mfma_f32_16x16x32_bf16(wfrag[1][2 + i], a, acc1, 0, 0, 0);
      }
    } else {
#pragma unroll
      for (int i = 0; i < KSTEPS; ++i) { // h1_t | h2_prev direct
        short8 a = *(const short8*)&hfr[i];
        acc0 = __builtin_amdgcn_mfma_f32_16x16x32_bf16(wfrag[0][i], a, acc0, 0, 0, 0);
        acc1 = __builtin_amdgcn_mfma_f32_16x16x32_bf16(wfrag[1][i], a, acc1, 0, 0, 0);
      }
    }

    // ---- gates in-register (R12-proven lane layout) ----
    float hA, hB;
    {
      float i0 = sigm(acc0[0] + b4A[0]);
      float f0 = sigm(acc0[1] + b4A[1]);
      float g0 = tanh_f(acc0[2] + b4A[2]);
      float o0 = sigm(acc0[3] + b4A[3]);
      cA = f0 * cA + i0 * g0;
      hA = o0 * tanh_f(cA);
      float i1 = sigm(acc1[0] + b4B[0]);
      float f1 = sigm(acc1[1] + b4B[1]);
      float g1 = tanh_f(acc1[2] + b4B[2]);
      float o1 = sigm(acc1[3] + b4B[3]);
      cB = f1 * cB + i1 * g1;
      hB = o1 * tanh_f(cB);
    }
    // pack unit pairs (lane^16) and store to the ring (R12-proven mapping)
    {
      float hA2 = __shfl_xor(hA, 16);
      float hB2 = __shfl_xor(hB, 16);
      if ((quad & 1) == 0) {
        unsigned dwA = (unsigned)f2bf(hA) | ((unsigned)f2bf(hA2) << 16);
        unsigned dwB = (unsigned)f2bf(hB) | ((unsigned)f2bf(hB2) << 16);
        unsigned* dst = (unsigned*)(LAYER ? h2bc : h1bc);
        size_t base = (size_t)(t & (RING - 1)) * RSTEP + (size_t)gb * 4096 +
                      (size_t)gg * 256 + (size_t)(Mt * 16 + l15) * 8;
        sth<FAST>(dst + base + Np * 4 + (quad >> 1), dwA);
        sth<FAST>(dst + base + Np * 4 + 2 + (quad >> 1), dwB);
      }
    }

    // ---- signal: R12 verbatim (barrier drains all waves' stores) ----
    __syncthreads();
    if (tid == 0)
      sth<FAST>((unsigned*)mys, (unsigned)(t + 1));

    // ---- head: y[b, t-1] — distributed (2 batches/wg), ring reads
    //      (epilogue-proven mapping; slot overwrite >=7 pipeline steps away)
    if (LAYER == 1 && t > 0 && tid < 16) {
      int eb2 = 2 * gg + (tid >> 3), uc = tid & 7;
      const unsigned* base = (const unsigned*)h2bc +
          ((size_t)((t - 1) & (RING - 1)) * RSTEP + (size_t)gb * 4096);
      float sum = 0.f;
#pragma unroll
      for (int g = 0; g < 2; ++g) {
        const unsigned* src = base + (size_t)(2 * uc + g) * 256 + eb2 * 8;
#pragma unroll
        for (int j = 0; j < 8; ++j) {
          unsigned dw = ldh<FAST>(src + j);
          sum += bf2f((unsigned short)(dw & 0xFFFFu)) * wlinS[uc * 32 + g * 16 + 2 * j];
          sum += bf2f((unsigned short)(dw >> 16)) * wlinS[uc * 32 + g * 16 + 2 * j + 1];
        }
      }
      sum += __shfl_xor(sum, 1);
      sum += __shfl_xor(sum, 2);
      sum += __shfl_xor(sum, 4);
      if ((tid & 7) == 0)
        out[(size_t)(b0 + eb2) * T_LEN + (t - 1)] = sigm(sum + blinv);
    }
  }

  // ---- epilogue: y[:, 511] — R12 verbatim ----
  if (LAYER == 1) {
    if (wv == 0 && lane < 16) {
      const int* sl = c1s + lane * SLOTS;
      while (__hip_atomic_load(sl, __ATOMIC_RELAXED, __HIP_MEMORY_SCOPE_AGENT) < T_LEN) {
        __builtin_amdgcn_s_sleep(1);
      }
    }
    __syncthreads();
    if (FAST) inv_l1();
    if (tid < 16) {
      int eb2 = 2 * gg + (tid >> 3), uc = tid & 7;
      const unsigned* base = (const unsigned*)h2bc +
          ((size_t)(511 & (RING - 1)) * RSTEP + (size_t)gb * 4096);
      float sum = 0.f;
#pragma unroll
      for (int g = 0; g < 2; ++g) {
        const unsigned* src = base + (size_t)(2 * uc + g) * 256 + eb2 * 8;
#pragma unroll
        for (int j = 0; j < 8; ++j) {
          unsigned dw = ldh<FAST>(src + j);
          sum += bf2f((unsigned short)(dw & 0xFFFFu)) * wlinS[uc * 32 + g * 16 + 2 * j];
          sum += bf2f((unsigned short)(dw >> 16)) * wlinS[uc * 32 + g * 16 + 2 * j + 1];
        }
      }
      sum += __shfl_xor(sum, 1);
      sum += __shfl_xor(sum, 2);
      sum += __shfl_xor(sum, 4);
      if ((tid & 7) == 0)
        out[(size_t)(b0 + eb2) * T_LEN + 511] = sigm(sum + blinv);
    }
  }
}

// ---------------------------------------------------------------------------
extern "C" __global__ void __launch_bounds__(256, 1) lstm_persist(
    const float* __restrict__ x,
    const float* __restrict__ Wih0, const float* __restrict__ Whh0,
    const float* __restrict__ bih0, const float* __restrict__ bhh0,
    const float* __restrict__ Wih1, const float* __restrict__ Whh1,
    const float* __restrict__ bih1, const float* __restrict__ bhh1,
    const float* __restrict__ Wlin, const float* __restrict__ blin,
    float* __restrict__ out,
    unsigned short* __restrict__ h1bc, unsigned short* __restrict__ h2bc,
    int* __restrict__ cnt) {
  __shared__ unsigned short WL[NR][LDSK];    // 66560 B  bf16 [r][k]
  __shared__ unsigned short xA[MB][XLDS];    //  4608 B  x staging (layer0)
  __shared__ float biasS[NR];
  __shared__ float wlinS[HP];

  const int tid = threadIdx.x;
  const int wg = blockIdx.x;

  // ---- XCD discovery + dynamic clustering (R12 verbatim) ----
  const unsigned xcc = ((unsigned)__builtin_amdgcn_s_getreg(GETREG_XCC)) & 15u;
  if (tid == 0) {
    __hip_atomic_store(cnt + XCD_AT(wg), (int)xcc, __ATOMIC_RELAXED,
                       __HIP_MEMORY_SCOPE_AGENT);
    __hip_atomic_fetch_add(cnt + BAR_IDX, 1, __ATOMIC_ACQ_REL,
                           __HIP_MEMORY_SCOPE_AGENT);
    while (__hip_atomic_load(cnt + BAR_IDX, __ATOMIC_ACQUIRE,
                             __HIP_MEMORY_SCOPE_AGENT) < 256)
      __builtin_amdgcn_s_sleep(8);
  }
  __syncthreads();
  int* sx = (int*)&xA[0][0];   // xA as 256-int scratch (pre-zeroing)
  sx[tid] = __hip_atomic_load(cnt + XCD_AT(tid), __ATOMIC_RELAXED,
                              __HIP_MEMORY_SCOPE_AGENT);
  __syncthreads();
  const int myv = sx[wg];
  int rank = 0;
  unsigned long long hist = 0;
  bool ok = true;
  for (int j = 0; j < 256; ++j) {
    int v = sx[j];
    if ((unsigned)v > 7u) { ok = false; v = 0; }
    hist += 1ull << (v * 8);
    if (v == myv && j < wg) rank++;
  }
  ok = ok && (hist == 0x2020202020202020ull);   // exactly 32 wgs per XCD
  __syncthreads();   // sx (xA) free for zero-fill below

  // Roles: fast -> cluster = this XCD; slow -> static mapping + sc1 ops.
  int layer, gb, gg;
  if (ok) { gb = myv;       layer = rank >> 4;    gg = rank & 15; }
  else    { layer = wg >> 7; gb = (wg >> 4) & 7;  gg = wg & 15;   }
  const int b0 = gb * MB, u0 = gg * NU;

  // ---- one-time LDS fills ----
  {
    const float* Wih = layer ? Wih1 : Wih0;
    const float* Whh = layer ? Whh1 : Whh0;
    const float* bi = layer ? bih1 : bih0;
    const float* bh = layer ? bhh1 : bhh0;
    const int K = layer ? K1 : K0;
    const int xw = layer ? NH : NX;     // real width of input-part
    const int xofs = layer ? HP : XP;   // where h-part starts
    int r = tid >> 2, c = tid & 3;
    int lu = r >> 2, g = r & 3, ug = u0 + lu;
    int row = g * NH + ug;
    int kq = K >> 2;
    for (int k = c * kq; k < (c + 1) * kq; ++k) {
      float v = 0.f;
      if (ug < NH) {
        if (k < xw) v = Wih[(size_t)row * xw + k];
        else if (k >= xofs && k < xofs + NH) v = Whh[(size_t)row * NH + (k - xofs)];
      }
      WL[r][k] = f2bf(v);
    }
    if (tid < NR) {
      int lu2 = tid >> 2, g2 = tid & 3, ug2 = u0 + lu2;
      biasS[tid] = (ug2 < NH) ? (bi[g2 * NH + ug2] + bh[g2 * NH + ug2]) : 0.f;
    }
    if (tid < HP) wlinS[tid] = (tid < NH) ? Wlin[tid] : 0.f;
    for (int i = tid; i < MB * XLDS; i += 256) ((unsigned short*)xA)[i] = 0;
  }
  __syncthreads();

  float blinv = blin[0];
  int* c0s = cnt + gb * 16 * SLOTS;              // layer0 flags, batch-group gb
  int* c1s = cnt + (8 + gb) * 16 * SLOTS;        // layer1 flags
  int* mys = (layer ? c1s : c0s) + gg * SLOTS;   // own flag

  if (ok) {
    if (layer == 0)
      run_layer<K0 / 32, 0, true>(tid, gg, b0, u0, x, out, blinv, h1bc, h2bc,
                                  c0s, c1s, mys, WL, xA, biasS, wlinS);
    else
      run_layer<K1 / 32, 1, true>(tid, gg, b0, u0, x, out, blinv, h1bc, h2bc,
                                  c0s, c1s, mys, WL, xA, biasS, wlinS);
  } else {
    if (layer == 0)
      run_layer<K0 / 32, 0, false>(tid, gg, b0, u0, x, out, blinv, h1bc, h2bc,
                                   c0s, c1s, mys, WL, xA, biasS, wlinS);
    else
      run_layer<K1 / 32, 1, false>(tid, gg, b0, u0, x, out, blinv, h1bc, h2bc,
                                   c0s, c1s, mys, WL, xA, biasS, wlinS);
  }
}

extern "C" __global__ void prep_zero(int* cnt) {
  int i = blockIdx.x * 256 + threadIdx.x;
  if (i < NFLAG)   // flag slots incl. embedded barrier/xcd-id padding ints
    __hip_atomic_store(cnt + i, 0, __ATOMIC_RELAXED, __HIP_MEMORY_SCOPE_AGENT);
}

// ---------------------------------------------------------------------------
extern "C" void kernel_launch(void* const* d_in, const int* in_sizes, int n_in,
                              void* d_out, int out_size, void* d_ws, size_t ws_size,
                              hipStream_t stream) {
  const float* x    = (const float*)d_in[0];
  const float* Wih0 = (const float*)d_in[1];
  const float* Whh0 = (const float*)d_in[2];
  const float* bih0 = (const float*)d_in[3];
  const float* bhh0 = (const float*)d_in[4];
  const float* Wih1 = (const float*)d_in[5];
  const float* Whh1 = (const float*)d_in[6];
  const float* bih1 = (const float*)d_in[7];
  const float* bhh1 = (const float*)d_in[8];
  const float* Wlin = (const float*)d_in[9];
  const float* blin = (const float*)d_in[10];
  float* out = (float*)d_out;

  // workspace carve (same footprint as R3..R14): h rings 2x2MB | flags 16KB
  unsigned short* h1bc = (unsigned short*)d_ws;
  unsigned short* h2bc = h1bc + (size_t)RING * B_TOT * HP;
  int* cnt = (int*)((char*)d_ws + 2u * (size_t)RING * B_TOT * HP * sizeof(unsigned short));

  hipLaunchKernelGGL(prep_zero, dim3(16), dim3(256), 0, stream, cnt);

  void* args[] = {&x, &Wih0, &Whh0, &bih0, &bhh0, &Wih1, &Whh1, &bih1, &bhh1,
                  &Wlin, &blin, &out, &h1bc, &h2bc, &cnt};
  hipLaunchCooperativeKernel((void*)lstm_persist, dim3(256), dim3(256), args, 0u, stream);
}